// Round 1
// baseline (403.118 us; speedup 1.0000x reference)
//
#include <hip/hip_runtime.h>
#include <math.h>

#define B_ 64
#define T_ 1024
#define D_ 512
#define U_ 1024

typedef __bf16 bf16x8 __attribute__((ext_vector_type(8)));
typedef float f32x16 __attribute__((ext_vector_type(16)));
typedef unsigned int u32;

__device__ __forceinline__ float fast_tanh(float x) {
    float ax = fabsf(x);
    float e = __expf(2.0f * ax);
    float r = 1.0f - __fdividef(2.0f, e + 1.0f);
    return copysignf(r, x);
}

__device__ __forceinline__ u32 f2bf_pk(float lo, float hi) {
    u32 a = __float_as_uint(lo) + 0x8000u;
    u32 b = __float_as_uint(hi) + 0x8000u;
    return (a >> 16) | (b & 0xffff0000u);
}

// K_prep: blocks [0,256): W1 [D][U] fp32 -> W1F in MFMA-fragment order:
//   frag=(ut*16+kt)*2+ks holds B-frag for u-tile ut (32 u), k=kt*32+ks*16;
//   slot (frag,lane) = 8 bf16: u=ut*32+(lane&31), k0=kt*32+ks*16+(lane>>5)*8.
// blocks [256,512): ph[b][u] = hidden·W2 + W2_b + W1_b; first 128 of these
// also zero out_ctx for the atomic accumulation in ctx_kernel.
__global__ __launch_bounds__(256) void prep_kernel(
    const float* __restrict__ W1, const float* __restrict__ hidden,
    const float* __restrict__ W2, const float* __restrict__ W2b,
    const float* __restrict__ W1b,
    unsigned short* __restrict__ W1F, float* __restrict__ ph,
    float* __restrict__ ctx0) {
    if (blockIdx.x < 256) {
        const int gid  = blockIdx.x * 256 + threadIdx.x;  // 0..65535
        const int lane = gid & 63;
        const int frag = gid >> 6;                        // 0..1023
        const int ks = frag & 1;
        const int kt = (frag >> 1) & 15;
        const int ut = frag >> 5;
        const int u  = ut * 32 + (lane & 31);
        const int k0 = kt * 32 + ks * 16 + (lane >> 5) * 8;
        float f[8];
#pragma unroll
        for (int j = 0; j < 8; ++j) f[j] = W1[(size_t)(k0 + j) * U_ + u];
        uint4 w;
        w.x = f2bf_pk(f[0], f[1]);
        w.y = f2bf_pk(f[2], f[3]);
        w.z = f2bf_pk(f[4], f[5]);
        w.w = f2bf_pk(f[6], f[7]);
        *(uint4*)&W1F[(size_t)gid * 8] = w;
    } else {
        const int bx = blockIdx.x - 256;
        const int zi = bx * 256 + (int)threadIdx.x;
        if (zi < B_ * D_) ctx0[zi] = 0.f;
        const int u  = (bx & 3) * 256 + threadIdx.x;
        const int b  = bx >> 2;
        const float* h = hidden + b * D_;
        float acc = 0.f;
#pragma unroll 8
        for (int d = 0; d < D_; ++d) acc = fmaf(h[d], W2[(size_t)d * U_ + u], acc);
        ph[b * U_ + u] = acc + W2b[u] + W1b[u];
    }
}

// K2: fused bf16 32x32x16-MFMA GEMM + tanh + V-dot.
// v2 structure: ONE block per (b, t-tile) computes BOTH u-halves sequentially
// against a single staged A tile (stage work halved vs uh-pair grid).
// Exactly ONE barrier per block (post-stage). Cross-wave reduction moved to
// global partials lpart[(b*T+t)*16 + uh*8 + widx], summed in ctx_kernel, so
// epilogue(uh=0) and K-loop(uh=1) have no barrier between them -> waves
// de-synchronize and tanh VALU overlaps other waves' MFMAs. uh=1's first
// B-frags are prefetched before epilogue(0). s_setprio(1) around MFMA cluster.
__global__ __launch_bounds__(512, 4) void logits_mfma_kernel(
    const float* __restrict__ feat,          // [B,T,D] fp32
    const unsigned short* __restrict__ W1F,  // fragment-order bf16
    const float* __restrict__ ph,            // [B,U] biases folded
    const float* __restrict__ Vw,            // [U]
    float* __restrict__ lpart) {             // [B*T][16] partials
    __shared__ __align__(16) char As[65536];  // 16 panels x 64 rows x 64 B

    const int tid  = threadIdx.x;
    const int tt   = blockIdx.x;        // 0..15
    const int b    = blockIdx.y;
    const int t0   = tt * 64;
    const int lane = tid & 63;
    const int widx = tid >> 6;
    const int l31 = lane & 31, g = lane >> 5;

    // ---- stage A once: feat[b, t0..t0+64, :] fp32 -> bf16 swizzled panels ----
    {
        const int r  = tid >> 3;       // 0..63
        const int s0 = tid & 7;
        const float* src = feat + ((size_t)(b * T_ + t0 + r)) * D_;
        const int xr = (r >> 2) & 3;
#pragma unroll
        for (int i = 0; i < 8; ++i) {
            const int s = s0 + 8 * i;            // 16B slot in row
            const float4 v0 = *(const float4*)(src + s * 8);
            const float4 v1 = *(const float4*)(src + s * 8 + 4);
            uint4 w;
            w.x = f2bf_pk(v0.x, v0.y);
            w.y = f2bf_pk(v0.z, v0.w);
            w.z = f2bf_pk(v1.x, v1.y);
            w.w = f2bf_pk(v1.z, v1.w);
            const int panel = s >> 2, q = s & 3;
            *(uint4*)&As[panel * 4096 + r * 64 + (q ^ xr) * 16] = w;
        }
    }
    __syncthreads();   // the ONLY barrier in this kernel

    // B frag bases for the wave's u-strip in each u-half (u0 = uh*512+widx*64)
    const char* bb0 = (const char*)W1F + (size_t)(widx * 2) * 32768 + lane * 16;
    const char* bb1 = bb0 + (size_t)16 * 32768;

    f32x16 acc[2][2];
    bf16x8 b0[4], b1[4];

    auto loadB = [&](const char* bb, bf16x8* dst, int kt) {
#pragma unroll
        for (int nt = 0; nt < 2; ++nt)
#pragma unroll
            for (int ks = 0; ks < 2; ++ks)
                dst[nt * 2 + ks] =
                    *(const bf16x8*)(bb + nt * 32768 + (kt * 2 + ks) * 1024);
    };

    auto computeStep = [&](int kt, const bf16x8* bfr) {
        bf16x8 af[2][2];   // [ks][mt]
#pragma unroll
        for (int ks = 0; ks < 2; ++ks)
#pragma unroll
            for (int mt = 0; mt < 2; ++mt) {
                const int rr = mt * 32 + l31;
                const int q  = (2 * ks + g) ^ ((rr >> 2) & 3);
                af[ks][mt] = *(const bf16x8*)&As[kt * 4096 + rr * 64 + q * 16];
            }
        __builtin_amdgcn_s_setprio(1);
#pragma unroll
        for (int ks = 0; ks < 2; ++ks)
#pragma unroll
            for (int mt = 0; mt < 2; ++mt)
#pragma unroll
                for (int nt = 0; nt < 2; ++nt)
                    acc[mt][nt] = __builtin_amdgcn_mfma_f32_32x32x16_bf16(
                        af[ks][mt], bfr[nt * 2 + ks], acc[mt][nt], 0, 0, 0);
        __builtin_amdgcn_s_setprio(0);
    };

    loadB(bb0, b0, 0);
#pragma unroll
    for (int uh = 0; uh < 2; ++uh) {
        const char* bb = uh ? bb1 : bb0;
#pragma unroll
        for (int mt = 0; mt < 2; ++mt)
#pragma unroll
            for (int nt = 0; nt < 2; ++nt) acc[mt][nt] = (f32x16)(0.f);

        for (int kt = 0; kt < 16; kt += 2) {
            loadB(bb, b1, kt + 1);
            computeStep(kt, b0);
            if (kt + 2 < 16) loadB(bb, b0, kt + 2);
            computeStep(kt + 1, b1);
        }
        if (uh == 0) loadB(bb1, b0, 0);   // prefetch next pass under epilogue

        // ---- fused epilogue: tanh + V-dot, reduce over the wave's 64 u ----
        float lp[2][16];
#pragma unroll
        for (int mt = 0; mt < 2; ++mt)
#pragma unroll
            for (int r = 0; r < 16; ++r) lp[mt][r] = 0.f;

#pragma unroll
        for (int nt = 0; nt < 2; ++nt) {
            const int u = uh * 512 + widx * 64 + nt * 32 + l31;
            const float phv = ph[b * U_ + u];
            const float vw  = Vw[u];
#pragma unroll
            for (int mt = 0; mt < 2; ++mt)
#pragma unroll
                for (int r = 0; r < 16; ++r)
                    lp[mt][r] = fmaf(vw, fast_tanh(acc[mt][nt][r] + phv), lp[mt][r]);
        }
#pragma unroll
        for (int mt = 0; mt < 2; ++mt)
#pragma unroll
            for (int r = 0; r < 16; ++r) {
                float v = lp[mt][r];
                v += __shfl_xor(v, 1);
                v += __shfl_xor(v, 2);
                v += __shfl_xor(v, 4);
                v += __shfl_xor(v, 8);
                v += __shfl_xor(v, 16);
                lp[mt][r] = v;
            }
        if (l31 == 0) {
#pragma unroll
            for (int mt = 0; mt < 2; ++mt)
#pragma unroll
                for (int r = 0; r < 16; ++r) {
                    const int row = mt * 32 + (r & 3) + 8 * (r >> 2) + 4 * g;
                    lpart[((size_t)(b * T_ + t0 + row)) * 16 + uh * 8 + widx] =
                        lp[mt][r];
                }
        }
    }
}

// K3: fused softmax + attn-write + context accumulation. grid (8 seg, B),
// block 512. Sums the 16 logit partials per t (L2-hot), computes softmax,
// writes its own attn t-slice, then atomically accumulates its 32-t context
// contribution into out_ctx (zeroed by prep_kernel).
__global__ __launch_bounds__(512) void ctx_kernel(
    const float* __restrict__ feat, const float* __restrict__ lpart,
    float* __restrict__ attn, float* __restrict__ ctx_out) {
    const int b   = blockIdx.y;
    const int seg = blockIdx.x;
    const int tid = threadIdx.x;
    __shared__ float wls[1024];
    __shared__ float redm[8];
    __shared__ float reds[8];

    float v[2];
    float mx = -3.4e38f;
#pragma unroll
    for (int j = 0; j < 2; ++j) {
        const float4* p =
            (const float4*)&lpart[((size_t)(b * T_) + tid + 512 * j) * 16];
        const float4 a = p[0], c = p[1], d = p[2], e = p[3];
        v[j] = ((a.x + a.y) + (a.z + a.w)) + ((c.x + c.y) + (c.z + c.w)) +
               ((d.x + d.y) + (d.z + d.w)) + ((e.x + e.y) + (e.z + e.w));
        mx = fmaxf(mx, v[j]);
    }
#pragma unroll
    for (int off = 32; off > 0; off >>= 1) mx = fmaxf(mx, __shfl_xor(mx, off));
    if ((tid & 63) == 0) redm[tid >> 6] = mx;
    __syncthreads();
    mx = fmaxf(fmaxf(fmaxf(redm[0], redm[1]), fmaxf(redm[2], redm[3])),
               fmaxf(fmaxf(redm[4], redm[5]), fmaxf(redm[6], redm[7])));
    float s = 0.f;
#pragma unroll
    for (int j = 0; j < 2; ++j) {
        v[j] = __expf(v[j] - mx);
        s += v[j];
    }
#pragma unroll
    for (int off = 32; off > 0; off >>= 1) s += __shfl_xor(s, off);
    if ((tid & 63) == 0) reds[tid >> 6] = s;
    __syncthreads();
    s = ((reds[0] + reds[1]) + (reds[2] + reds[3])) +
        ((reds[4] + reds[5]) + (reds[6] + reds[7]));
    const float inv = 1.0f / s;
    wls[tid]       = v[0] * inv;
    wls[tid + 512] = v[1] * inv;
    __syncthreads();

    // attn write: own slice only
    if (tid < 128) attn[b * T_ + seg * 128 + tid] = wls[seg * 128 + tid];

    // context over this block's 128 t (4 quarters of 32 t)
    const int q  = tid >> 7;
    const int d4 = (tid & 127) * 4;
    const int t0 = seg * 128 + q * 32;
    const float* fb = feat + ((size_t)(b * T_ + t0)) * D_ + d4;
    const float* wb = &wls[t0];
    float4 acc = {0.f, 0.f, 0.f, 0.f};
#pragma unroll 4
    for (int t = 0; t < 32; ++t) {
        const float w  = wb[t];
        const float4 f = *(const float4*)&fb[(size_t)t * D_];
        acc.x = fmaf(w, f.x, acc.x);
        acc.y = fmaf(w, f.y, acc.y);
        acc.z = fmaf(w, f.z, acc.z);
        acc.w = fmaf(w, f.w, acc.w);
    }
    float* dst = ctx_out + b * D_ + d4;
    atomicAdd(dst + 0, acc.x);
    atomicAdd(dst + 1, acc.y);
    atomicAdd(dst + 2, acc.z);
    atomicAdd(dst + 3, acc.w);
}

extern "C" void kernel_launch(void* const* d_in, const int* in_sizes, int n_in,
                              void* d_out, int out_size, void* d_ws, size_t ws_size,
                              hipStream_t stream) {
    const float* feat   = (const float*)d_in[0];
    const float* hidden = (const float*)d_in[1];
    const float* W1w    = (const float*)d_in[2];
    const float* W1b    = (const float*)d_in[3];
    const float* W2w    = (const float*)d_in[4];
    const float* W2b    = (const float*)d_in[5];
    const float* Vw     = (const float*)d_in[6];
    // V_b cancels in softmax and doesn't affect context.

    float* out_ctx  = (float*)d_out;             // [B,D]
    float* out_attn = out_ctx + B_ * D_;         // [B,T]

    unsigned short* W1F = (unsigned short*)d_ws;             // U*D bf16 = 1 MB
    float* ph     = (float*)(W1F + (size_t)U_ * D_);         // B*U
    float* lpart  = ph + B_ * U_;                            // B*T*16 = 4 MB

    prep_kernel<<<512, 256, 0, stream>>>(W1w, hidden, W2w, W2b, W1b, W1F, ph,
                                         out_ctx);
    logits_mfma_kernel<<<dim3(16, B_), 512, 0, stream>>>(feat, W1F, ph, Vw,
                                                         lpart);
    ctx_kernel<<<dim3(8, B_), 512, 0, stream>>>(feat, lpart, out_attn, out_ctx);
}

// Round 2
// 366.790 us; speedup vs baseline: 1.0990x; 1.0990x over previous
//
#include <hip/hip_runtime.h>
#include <math.h>

#define B_ 64
#define T_ 1024
#define D_ 512
#define U_ 1024

typedef __bf16 bf16x8 __attribute__((ext_vector_type(8)));
typedef float f32x16 __attribute__((ext_vector_type(16)));
typedef unsigned int u32;

__device__ __forceinline__ float fast_tanh(float x) {
    float ax = fabsf(x);
    float e = __expf(2.0f * ax);
    float r = 1.0f - __fdividef(2.0f, e + 1.0f);
    return copysignf(r, x);
}

__device__ __forceinline__ u32 f2bf_pk(float lo, float hi) {
    u32 a = __float_as_uint(lo) + 0x8000u;
    u32 b = __float_as_uint(hi) + 0x8000u;
    return (a >> 16) | (b & 0xffff0000u);
}

// K_prep: blocks [0,256): W1 [D][U] fp32 -> W1F in MFMA-fragment order:
//   frag=(ut*16+kt)*2+ks holds B-frag for u-tile ut (32 u), k=kt*32+ks*16;
//   slot (frag,lane) = 8 bf16: u=ut*32+(lane&31), k0=kt*32+ks*16+(lane>>5)*8.
// blocks [256,512): ph[b][u] = hidden·W2 + W2_b + W1_b; also zero out_ctx
// for the atomic accumulation in ctx_kernel.
__global__ __launch_bounds__(256) void prep_kernel(
    const float* __restrict__ W1, const float* __restrict__ hidden,
    const float* __restrict__ W2, const float* __restrict__ W2b,
    const float* __restrict__ W1b,
    unsigned short* __restrict__ W1F, float* __restrict__ ph,
    float* __restrict__ ctx0) {
    if (blockIdx.x < 256) {
        const int gid  = blockIdx.x * 256 + threadIdx.x;  // 0..65535
        const int lane = gid & 63;
        const int frag = gid >> 6;                        // 0..1023
        const int ks = frag & 1;
        const int kt = (frag >> 1) & 15;
        const int ut = frag >> 5;
        const int u  = ut * 32 + (lane & 31);
        const int k0 = kt * 32 + ks * 16 + (lane >> 5) * 8;
        float f[8];
#pragma unroll
        for (int j = 0; j < 8; ++j) f[j] = W1[(size_t)(k0 + j) * U_ + u];
        uint4 w;
        w.x = f2bf_pk(f[0], f[1]);
        w.y = f2bf_pk(f[2], f[3]);
        w.z = f2bf_pk(f[4], f[5]);
        w.w = f2bf_pk(f[6], f[7]);
        *(uint4*)&W1F[(size_t)gid * 8] = w;
    } else {
        const int bx = blockIdx.x - 256;
        const int zi = bx * 256 + (int)threadIdx.x;
        if (zi < B_ * D_) ctx0[zi] = 0.f;
        const int u  = (bx & 3) * 256 + threadIdx.x;
        const int b  = bx >> 2;
        const float* h = hidden + b * D_;
        float acc = 0.f;
#pragma unroll 8
        for (int d = 0; d < D_; ++d) acc = fmaf(h[d], W2[(size_t)d * U_ + u], acc);
        ph[b * U_ + u] = acc + W2b[u] + W1b[u];
    }
}

// K2: fused bf16 32x32x16-MFMA GEMM + tanh + V-dot.
// One block per (b, 64-t tile); both u-halves computed sequentially against a
// single staged A tile. Exactly ONE barrier (post-stage). Cross-u reduction:
// per-wave multi-value shfl tree (31 shfls) leaves the full u-strip sum for a
// DISTINCT row in each of the 64 lanes -> one fully-coalesced 256B store per
// wave into lpart[slot=uh*8+widx][b][t]. (Round-1's 2-lane scattered store
// caused 202 MB of HBM RMW write traffic — this kills it.)
__global__ __launch_bounds__(512, 4) void logits_mfma_kernel(
    const float* __restrict__ feat,          // [B,T,D] fp32
    const unsigned short* __restrict__ W1F,  // fragment-order bf16
    const float* __restrict__ ph,            // [B,U] biases folded
    const float* __restrict__ Vw,            // [U]
    float* __restrict__ lpart) {             // [16][B][T] partials
    __shared__ __align__(16) char As[65536];  // 16 panels x 64 rows x 64 B

    const int tid  = threadIdx.x;
    const int tt   = blockIdx.x;        // 0..15
    const int b    = blockIdx.y;
    const int t0   = tt * 64;
    const int lane = tid & 63;
    const int widx = tid >> 6;
    const int l31 = lane & 31, g = lane >> 5;

    // ---- stage A once: feat[b, t0..t0+64, :] fp32 -> bf16 swizzled panels ----
    {
        const int r  = tid >> 3;       // 0..63
        const int s0 = tid & 7;
        const float* src = feat + ((size_t)(b * T_ + t0 + r)) * D_;
        const int xr = (r >> 2) & 3;
#pragma unroll
        for (int i = 0; i < 8; ++i) {
            const int s = s0 + 8 * i;            // 16B slot in row
            const float4 v0 = *(const float4*)(src + s * 8);
            const float4 v1 = *(const float4*)(src + s * 8 + 4);
            uint4 w;
            w.x = f2bf_pk(v0.x, v0.y);
            w.y = f2bf_pk(v0.z, v0.w);
            w.z = f2bf_pk(v1.x, v1.y);
            w.w = f2bf_pk(v1.z, v1.w);
            const int panel = s >> 2, q = s & 3;
            *(uint4*)&As[panel * 4096 + r * 64 + (q ^ xr) * 16] = w;
        }
    }
    __syncthreads();   // the ONLY barrier in this kernel

    // B frag bases for the wave's u-strip in each u-half (u0 = uh*512+widx*64)
    const char* bb0 = (const char*)W1F + (size_t)(widx * 2) * 32768 + lane * 16;
    const char* bb1 = bb0 + (size_t)16 * 32768;

    f32x16 acc[2][2];
    bf16x8 b0[4], b1[4];

    auto loadB = [&](const char* bb, bf16x8* dst, int kt) {
#pragma unroll
        for (int nt = 0; nt < 2; ++nt)
#pragma unroll
            for (int ks = 0; ks < 2; ++ks)
                dst[nt * 2 + ks] =
                    *(const bf16x8*)(bb + nt * 32768 + (kt * 2 + ks) * 1024);
    };

    auto computeStep = [&](int kt, const bf16x8* bfr) {
        bf16x8 af[2][2];   // [ks][mt]
#pragma unroll
        for (int ks = 0; ks < 2; ++ks)
#pragma unroll
            for (int mt = 0; mt < 2; ++mt) {
                const int rr = mt * 32 + l31;
                const int q  = (2 * ks + g) ^ ((rr >> 2) & 3);
                af[ks][mt] = *(const bf16x8*)&As[kt * 4096 + rr * 64 + q * 16];
            }
        __builtin_amdgcn_s_setprio(1);
#pragma unroll
        for (int ks = 0; ks < 2; ++ks)
#pragma unroll
            for (int mt = 0; mt < 2; ++mt)
#pragma unroll
                for (int nt = 0; nt < 2; ++nt)
                    acc[mt][nt] = __builtin_amdgcn_mfma_f32_32x32x16_bf16(
                        af[ks][mt], bfr[nt * 2 + ks], acc[mt][nt], 0, 0, 0);
        __builtin_amdgcn_s_setprio(0);
    };

    loadB(bb0, b0, 0);
#pragma unroll
    for (int uh = 0; uh < 2; ++uh) {
        const char* bb = uh ? bb1 : bb0;
#pragma unroll
        for (int mt = 0; mt < 2; ++mt)
#pragma unroll
            for (int nt = 0; nt < 2; ++nt) acc[mt][nt] = (f32x16)(0.f);

        for (int kt = 0; kt < 16; kt += 2) {
            loadB(bb, b1, kt + 1);
            computeStep(kt, b0);
            if (kt + 2 < 16) loadB(bb, b0, kt + 2);
            computeStep(kt + 1, b1);
        }
        if (uh == 0) loadB(bb1, b0, 0);   // prefetch next pass under epilogue

        // ---- fused epilogue: tanh + V-dot into flat v[32] ----
        float v[32];
#pragma unroll
        for (int i = 0; i < 32; ++i) v[i] = 0.f;

#pragma unroll
        for (int nt = 0; nt < 2; ++nt) {
            const int u = uh * 512 + widx * 64 + nt * 32 + l31;
            const float phv = ph[b * U_ + u];
            const float vw  = Vw[u];
#pragma unroll
            for (int mt = 0; mt < 2; ++mt)
#pragma unroll
                for (int r = 0; r < 16; ++r)
                    v[mt * 16 + r] =
                        fmaf(vw, fast_tanh(acc[mt][nt][r] + phv), v[mt * 16 + r]);
        }

        // ---- multi-value tree reduce over the 32 lanes of each half ----
        // After 5 stages lane p(=l31) holds the full sum of v[p] across its
        // half; v[p]=value for (mt=p>>4, r=p&15) -> row below. 31 shfls total.
#pragma unroll
        for (int s = 0; s < 5; ++s) {
            const int pb = 1 << s;
            const bool hi = (l31 & pb) != 0;
#pragma unroll
            for (int j = 0; j < (16 >> s); ++j) {
                const float a = v[2 * j];
                const float c = v[2 * j + 1];
                const float keep = hi ? c : a;
                const float send = hi ? a : c;
                v[j] = keep + __shfl_xor(send, pb);
            }
        }
        const int row =
            (l31 & 3) + 8 * ((l31 >> 2) & 3) + 4 * g + 32 * (l31 >> 4);
        lpart[((size_t)(uh * 8 + widx)) * (B_ * T_) + (size_t)b * T_ + t0 + row] =
            v[0];
    }
}

// K3: fused softmax + attn-write + context accumulation. grid (8 seg, B),
// block 512. Sums the 16 logit partial slots per t (stride B*T, coalesced,
// L2-hot), computes softmax, writes its own attn t-slice, then atomically
// accumulates its 128-t context contribution into out_ctx (zeroed by prep).
__global__ __launch_bounds__(512) void ctx_kernel(
    const float* __restrict__ feat, const float* __restrict__ lpart,
    float* __restrict__ attn, float* __restrict__ ctx_out) {
    const int b   = blockIdx.y;
    const int seg = blockIdx.x;
    const int tid = threadIdx.x;
    __shared__ float wls[1024];
    __shared__ float redm[8];
    __shared__ float reds[8];

    float v[2];
    float mx = -3.4e38f;
#pragma unroll
    for (int j = 0; j < 2; ++j) {
        const int t = b * T_ + tid + 512 * j;
        float s0 = 0.f, s1 = 0.f;
#pragma unroll
        for (int sl = 0; sl < 8; ++sl) {
            s0 += lpart[(size_t)(2 * sl) * (B_ * T_) + t];
            s1 += lpart[(size_t)(2 * sl + 1) * (B_ * T_) + t];
        }
        v[j] = s0 + s1;
        mx = fmaxf(mx, v[j]);
    }
#pragma unroll
    for (int off = 32; off > 0; off >>= 1) mx = fmaxf(mx, __shfl_xor(mx, off));
    if ((tid & 63) == 0) redm[tid >> 6] = mx;
    __syncthreads();
    mx = fmaxf(fmaxf(fmaxf(redm[0], redm[1]), fmaxf(redm[2], redm[3])),
               fmaxf(fmaxf(redm[4], redm[5]), fmaxf(redm[6], redm[7])));
    float s = 0.f;
#pragma unroll
    for (int j = 0; j < 2; ++j) {
        v[j] = __expf(v[j] - mx);
        s += v[j];
    }
#pragma unroll
    for (int off = 32; off > 0; off >>= 1) s += __shfl_xor(s, off);
    if ((tid & 63) == 0) reds[tid >> 6] = s;
    __syncthreads();
    s = ((reds[0] + reds[1]) + (reds[2] + reds[3])) +
        ((reds[4] + reds[5]) + (reds[6] + reds[7]));
    const float inv = 1.0f / s;
    wls[tid]       = v[0] * inv;
    wls[tid + 512] = v[1] * inv;
    __syncthreads();

    // attn write: own slice only
    if (tid < 128) attn[b * T_ + seg * 128 + tid] = wls[seg * 128 + tid];

    // context over this block's 128 t (4 quarters of 32 t)
    const int q  = tid >> 7;
    const int d4 = (tid & 127) * 4;
    const int t0 = seg * 128 + q * 32;
    const float* fb = feat + ((size_t)(b * T_ + t0)) * D_ + d4;
    const float* wb = &wls[t0];
    float4 acc = {0.f, 0.f, 0.f, 0.f};
#pragma unroll 4
    for (int t = 0; t < 32; ++t) {
        const float w  = wb[t];
        const float4 f = *(const float4*)&fb[(size_t)t * D_];
        acc.x = fmaf(w, f.x, acc.x);
        acc.y = fmaf(w, f.y, acc.y);
        acc.z = fmaf(w, f.z, acc.z);
        acc.w = fmaf(w, f.w, acc.w);
    }
    float* dst = ctx_out + b * D_ + d4;
    atomicAdd(dst + 0, acc.x);
    atomicAdd(dst + 1, acc.y);
    atomicAdd(dst + 2, acc.z);
    atomicAdd(dst + 3, acc.w);
}

extern "C" void kernel_launch(void* const* d_in, const int* in_sizes, int n_in,
                              void* d_out, int out_size, void* d_ws, size_t ws_size,
                              hipStream_t stream) {
    const float* feat   = (const float*)d_in[0];
    const float* hidden = (const float*)d_in[1];
    const float* W1w    = (const float*)d_in[2];
    const float* W1b    = (const float*)d_in[3];
    const float* W2w    = (const float*)d_in[4];
    const float* W2b    = (const float*)d_in[5];
    const float* Vw     = (const float*)d_in[6];
    // V_b cancels in softmax and doesn't affect context.

    float* out_ctx  = (float*)d_out;             // [B,D]
    float* out_attn = out_ctx + B_ * D_;         // [B,T]

    unsigned short* W1F = (unsigned short*)d_ws;             // U*D bf16 = 1 MB
    float* ph     = (float*)(W1F + (size_t)U_ * D_);         // B*U
    float* lpart  = ph + B_ * U_;                            // 16*B*T = 4 MB

    prep_kernel<<<512, 256, 0, stream>>>(W1w, hidden, W2w, W2b, W1b, W1F, ph,
                                         out_ctx);
    logits_mfma_kernel<<<dim3(16, B_), 512, 0, stream>>>(feat, W1F, ph, Vw,
                                                         lpart);
    ctx_kernel<<<dim3(8, B_), 512, 0, stream>>>(feat, lpart, out_attn, out_ctx);
}